// Round 4
// baseline (459.054 us; speedup 1.0000x reference)
//
#include <hip/hip_runtime.h>
#include <stdint.h>

#define TOKENS 8192
#define OUT_F  4096
#define IN_F   4096
#define RNK    8
#define RPB    4
#define KPRUNE 8388608u
#define CAP3   16384u

typedef unsigned short u16;
typedef float  f32x4  __attribute__((ext_vector_type(4)));
typedef short  bf16x8 __attribute__((ext_vector_type(8)));
typedef unsigned short u16x4 __attribute__((ext_vector_type(4)));
typedef unsigned short u16x8 __attribute__((ext_vector_type(8)));

// ---- workspace layout (bytes) ----
#define XB_OFF    0ull                 // xB  : 8192*4096 bf16 = 64 MiB
#define WB_OFF    67108864ull          // wB  : 4096*4096 bf16 = 32 MiB
#define KEYS_OFF  100663296ull         // keys: 4096*4096 u32  = 64 MiB
#define CTL_OFF   167772160ull
//   ctl: h1[4096] h2[4096] sel[8] cnt3[1] list3[CAP3]
#define H1_OFF    0
#define H2_OFF    16384
#define SEL_OFF   32768
#define CNT3_OFF  32800
#define LIST3_OFF 32804
#define CTL_ZERO_U32 8201              // h1+h2+sel+cnt3

__device__ __forceinline__ u16 f2bf(float f) {
    uint32_t u = __float_as_uint(f);
    u += 0x7fffu + ((u >> 16) & 1u);   // RNE
    return (u16)(u >> 16);
}

__device__ __forceinline__ uint32_t fkey(float s) {
    uint32_t u = __float_as_uint(s);
    return (u & 0x80000000u) ? ~u : (u | 0x80000000u);
}

// ---------------- x -> bf16 (+ ctl zeroing folded in) ----------------
__global__ void convx_kernel(const float* __restrict__ x, u16* __restrict__ xB,
                             uint32_t* __restrict__ ctl)
{
    const int t = threadIdx.x;
    if (blockIdx.x < 34) {
        const int i = blockIdx.x * 256 + t;
        if (i < CTL_ZERO_U32) ctl[i] = 0u;
    }
    const size_t idx = (size_t)blockIdx.x * 256 + t;
    const float4* xv = (const float4*)x;
    float4 a = xv[idx*2];
    float4 b = xv[idx*2 + 1];
    u16x8 o;
    o[0]=f2bf(a.x); o[1]=f2bf(a.y); o[2]=f2bf(a.z); o[3]=f2bf(a.w);
    o[4]=f2bf(b.x); o[5]=f2bf(b.y); o[6]=f2bf(b.z); o[7]=f2bf(b.w);
    *((u16x8*)xB + idx) = o;
}

// ---------------- prep: w, keys, bf16 w, 12-bit histogram (4 rows/block, float4) ----------------
__global__ void prep_kernel(const float* __restrict__ W, const float* __restrict__ U,
                            const float* __restrict__ V, const float* __restrict__ A,
                            const float* __restrict__ B, const float* __restrict__ R,
                            const float* __restrict__ C, u16* __restrict__ wB,
                            uint32_t* __restrict__ keys, uint32_t* __restrict__ hist1)
{
    __shared__ uint32_t lh[2][4096];   // 2 sub-hists halve hot-bin atomic contention
    const int o0 = blockIdx.x * RPB, t = threadIdx.x;
    uint32_t* lhs = lh[t & 1];
    for (int b = t; b < 8192; b += 256) ((uint32_t*)lh)[b] = 0u;
    float uu[RPB][RNK], aa[RPB][RNK], ro[RPB];
#pragma unroll
    for (int r0 = 0; r0 < RPB; ++r0) {
#pragma unroll
        for (int r = 0; r < RNK; ++r) {
            uu[r0][r] = U[(o0+r0)*RNK + r];
            aa[r0][r] = A[(o0+r0)*RNK + r];
        }
        ro[r0] = R[o0 + r0];
    }
    __syncthreads();
    for (int j = 0; j < IN_F/1024; ++j) {
        const int i = j*1024 + t*4;
        const float4 cc = *(const float4*)&C[i];
#pragma unroll
        for (int r0 = 0; r0 < RPB; ++r0) {
            float4 wv = *(const float4*)&W[(size_t)(o0+r0)*IN_F + i];
#pragma unroll
            for (int r = 0; r < RNK; ++r) {
                const float4 v4 = *(const float4*)&V[r*IN_F + i];
                const float u0 = uu[r0][r];
                wv.x = fmaf(u0, v4.x, wv.x); wv.y = fmaf(u0, v4.y, wv.y);
                wv.z = fmaf(u0, v4.z, wv.z); wv.w = fmaf(u0, v4.w, wv.w);
            }
            float4 s;
            s.x = fabsf(wv.x); s.y = fabsf(wv.y); s.z = fabsf(wv.z); s.w = fabsf(wv.w);
#pragma unroll
            for (int r = 0; r < RNK; ++r) {
                const float4 b4 = *(const float4*)&B[r*IN_F + i];
                const float a0 = aa[r0][r];
                s.x = fmaf(a0, b4.x, s.x); s.y = fmaf(a0, b4.y, s.y);
                s.z = fmaf(a0, b4.z, s.z); s.w = fmaf(a0, b4.w, s.w);
            }
            const float rr = ro[r0];
            s.x += rr + cc.x; s.y += rr + cc.y; s.z += rr + cc.z; s.w += rr + cc.w;
            uint4 k4;
            k4.x = fkey(s.x); k4.y = fkey(s.y); k4.z = fkey(s.z); k4.w = fkey(s.w);
            *(uint4*)&keys[(size_t)(o0+r0)*IN_F + i] = k4;
            u16x4 w4;
            w4[0] = f2bf(wv.x); w4[1] = f2bf(wv.y); w4[2] = f2bf(wv.z); w4[3] = f2bf(wv.w);
            *(u16x4*)&wB[(size_t)(o0+r0)*IN_F + i] = w4;
            atomicAdd(&lhs[k4.x >> 20], 1u);
            atomicAdd(&lhs[k4.y >> 20], 1u);
            atomicAdd(&lhs[k4.z >> 20], 1u);
            atomicAdd(&lhs[k4.w >> 20], 1u);
        }
    }
    __syncthreads();
    for (int b = t; b < 4096; b += 256) {
        const uint32_t c = lh[0][b] + lh[1][b];
        if (c) atomicAdd(&hist1[b], c);
    }
}

// ---------------- k-th select over a 4096-bin histogram ----------------
// mode 0: hist1 (key>>20),        k=KPRUNE        -> sel[0]=b1, sel[1]=below
// mode 1: hist2 ((key>>8)&FFF),   k=KPRUNE-sel[1] -> sel[2]=b2, sel[3]=total_below(24-bit prefix)
__global__ void select_kernel(const uint32_t* __restrict__ hist, uint32_t* sel, int mode)
{
    __shared__ uint32_t lh[4096];
    __shared__ uint32_t part[256];
    __shared__ uint32_t sseg[2];
    const int t = threadIdx.x;
    const uint32_t c1v = sel[1];
    const uint32_t k = (mode == 0) ? KPRUNE : (KPRUNE - c1v);
    for (int b = t; b < 4096; b += 256) lh[b] = hist[b];
    __syncthreads();
    uint32_t s = 0;
    for (int j = 0; j < 16; ++j) s += lh[t*16 + j];
    part[t] = s;
    __syncthreads();
    uint32_t pre = 0;
    for (int tt = 0; tt < t; ++tt) pre += part[tt];
    if (pre < k && pre + part[t] >= k) { sseg[0] = (uint32_t)t; sseg[1] = pre; }
    __syncthreads();
    const int seg = (int)sseg[0];
    const uint32_t accb = sseg[1];
    if (t < 16) {
        uint32_t pre2 = 0;
        for (int j = 0; j < t; ++j) pre2 += lh[seg*16 + j];
        const uint32_t c = lh[seg*16 + t];
        const uint32_t below = accb + pre2;
        if (below < k && below + c >= k) {
            const uint32_t bin = (uint32_t)(seg*16 + t);
            if (mode == 0) { sel[0] = bin; sel[1] = below; }
            else           { sel[2] = bin; sel[3] = c1v + below; }
        }
    }
}

// ---------------- hist level 2 ----------------
__global__ void hist2_kernel(const uint32_t* __restrict__ keys, const uint32_t* __restrict__ sel,
                             uint32_t* __restrict__ hist2)
{
    __shared__ uint32_t lh[4096];
    const int o = blockIdx.x, t = threadIdx.x;
    const uint32_t b1 = sel[0];
    for (int b = t; b < 4096; b += 256) lh[b] = 0u;
    __syncthreads();
    const uint32_t* kp = keys + (size_t)o*IN_F + t*16;
#pragma unroll
    for (int q = 0; q < 4; ++q) {
        uint4 kv = *(const uint4*)(kp + q*4);
        if ((kv.x >> 20) == b1) atomicAdd(&lh[(kv.x >> 8) & 0xFFFu], 1u);
        if ((kv.y >> 20) == b1) atomicAdd(&lh[(kv.y >> 8) & 0xFFFu], 1u);
        if ((kv.z >> 20) == b1) atomicAdd(&lh[(kv.z >> 8) & 0xFFFu], 1u);
        if ((kv.w >> 20) == b1) atomicAdd(&lh[(kv.w >> 8) & 0xFFFu], 1u);
    }
    __syncthreads();
    for (int b = t; b < 4096; b += 256) { uint32_t c = lh[b]; if (c) atomicAdd(&hist2[b], c); }
}

// ---------------- collect3: gather keys matching the 24-bit prefix ----------------
// packed entry: (flat_idx << 8) | (key & 0xFF)   (flat_idx < 2^24)
__global__ void collect3_kernel(const uint32_t* __restrict__ keys, const uint32_t* __restrict__ sel,
                                uint32_t* __restrict__ cnt3, uint32_t* __restrict__ list3)
{
    const uint32_t pfx = (sel[0] << 12) | sel[2];
    const size_t base = ((size_t)blockIdx.x * 256 + threadIdx.x) * 16;
#pragma unroll
    for (int q = 0; q < 4; ++q) {
        uint4 kv = *(const uint4*)(keys + base + q*4);
        const uint32_t i0 = (uint32_t)(base + q*4);
        if ((kv.x >> 8) == pfx) { uint32_t s = atomicAdd(cnt3, 1u); if (s < CAP3) list3[s] = ((i0+0u) << 8) | (kv.x & 0xFFu); }
        if ((kv.y >> 8) == pfx) { uint32_t s = atomicAdd(cnt3, 1u); if (s < CAP3) list3[s] = ((i0+1u) << 8) | (kv.y & 0xFFu); }
        if ((kv.z >> 8) == pfx) { uint32_t s = atomicAdd(cnt3, 1u); if (s < CAP3) list3[s] = ((i0+2u) << 8) | (kv.z & 0xFFu); }
        if ((kv.w >> 8) == pfx) { uint32_t s = atomicAdd(cnt3, 1u); if (s < CAP3) list3[s] = ((i0+3u) << 8) | (kv.w & 0xFFu); }
    }
}

// ---------------- selfix: final 8-bit select + exact stable tie pruning ----------------
__global__ void selfix_kernel(uint32_t* sel, const uint32_t* __restrict__ cnt3,
                              const uint32_t* __restrict__ list3, u16* __restrict__ wB)
{
    __shared__ uint32_t lst[CAP3];
    __shared__ uint32_t hist[256];
    __shared__ uint32_t sv[2];
    const int t = threadIdx.x;
    uint32_t n = *cnt3; if (n > CAP3) n = CAP3;
    hist[t] = 0u;
    __syncthreads();
    for (uint32_t i = t; i < n; i += 256) {
        const uint32_t e = list3[i];
        lst[i] = e;
        atomicAdd(&hist[e & 0xFFu], 1u);
    }
    __syncthreads();
    const uint32_t k3 = KPRUNE - sel[3];     // >= 1, <= n
    uint32_t pre = 0;
    for (int b = 0; b < t; ++b) pre += hist[b];
    if (pre < k3 && pre + hist[t] >= k3) {
        sv[0] = (uint32_t)t;
        sv[1] = k3 - pre;                    // ties to prune (>=1)
        sel[4] = (sel[0] << 20) | (sel[2] << 8) | (uint32_t)t;   // exact threshold key
    }
    __syncthreads();
    const uint32_t b3 = sv[0], p = sv[1];
    for (uint32_t i = t; i < n; i += 256) {
        const uint32_t e = lst[i];
        if ((e & 0xFFu) != b3) continue;
        uint32_t rank = 0;
        for (uint32_t j = 0; j < n; ++j) {
            const uint32_t f = lst[j];
            rank += ((f & 0xFFu) == b3 && f < e) ? 1u : 0u;   // same low8 -> compares flat idx
        }
        if (rank < p) wB[e >> 8] = 0u;
    }
}

// ---------------- apply: prune key < thr (ties already handled by selfix) ----------------
__global__ void apply_kernel(const uint32_t* __restrict__ keys, const uint32_t* __restrict__ sel,
                             u16* __restrict__ wB)
{
    const uint32_t thr = sel[4];
    const size_t base = ((size_t)blockIdx.x * 256 + threadIdx.x) * 16;
    uint32_t kv[16];
#pragma unroll
    for (int q = 0; q < 4; ++q) *(uint4*)(kv + q*4) = *(const uint4*)(keys + base + q*4);
    uint4 wraw[2];
    wraw[0] = *(const uint4*)(wB + base);
    wraw[1] = *(const uint4*)(wB + base + 8);
    u16* wv = (u16*)wraw;
#pragma unroll
    for (int e = 0; e < 16; ++e) if (kv[e] < thr) wv[e] = 0u;
    *(uint4*)(wB + base)     = wraw[0];
    *(uint4*)(wB + base + 8) = wraw[1];
}

// ================= 256x256 8-phase bf16 NT GEMM =================
// BM=BN=256, BK=64, 8 waves (2M x 4N), LDS 128 KiB, T2 3-bit XOR swizzle
// (physical = logical ^ ((row&7)<<4), applied after the full logical offset),
// T1 bijective XCD-chunked blockIdx swizzle (each XCD owns 2 bn-columns x all bm).
#define LA0 0
#define LB0 32768
#define LA1 65536
#define LB1 98304

__device__ __forceinline__ void gl_lds16(const char* src, char* dst) {
    __builtin_amdgcn_global_load_lds((const __attribute__((address_space(1))) void*)src,
                                     (__attribute__((address_space(3))) void*)dst, 16, 0, 0);
}

__global__ __launch_bounds__(512, 2) void gemm256_kernel(const u16* __restrict__ xB,
                                                         const u16* __restrict__ wB,
                                                         const float* __restrict__ bias,
                                                         float* __restrict__ out)
{
    __shared__ char ldsc[131072];
    const int t    = threadIdx.x;
    const int lane = t & 63;
    const int wid  = t >> 6;
    const int wm   = wid >> 2;     // 0..1
    const int wn   = wid & 3;      // 0..3
    // T1: XCD-chunked bijective swizzle (nwg=512, 8 XCDs, 64 tiles/XCD)
    const int orig = blockIdx.x;
    const int tid  = (orig & 7) * 64 + (orig >> 3);
    const int bn   = tid >> 5;           // 0..15 : XCD x owns bn {2x,2x+1} -> wB panels L2-resident
    const int bm   = tid & 31;           // 0..31 : xB panels shared via LLC

    const int l15 = lane & 15;
    const int kb  = (lane >> 4) << 4;               // 0,16,32,48 bytes (k-group)
    const int sw  = (lane & 7) << 4;                // 3-bit XOR swizzle
    const int bA  = (16*wm + l15) * 128 + kb;       // + m*4096 + kk*64, then ^ sw
    const int bB  = (64*wn + l15) * 128 + kb;       // + ni*2048 + kk*64, then ^ sw

    // staging: linear LDS dest [half*16384 + issue*8192 + t*16]; pre-swizzled global source
    const int scol = ((t & 7) * 16) ^ (((t >> 3) & 7) << 4);
    const char* pA = (const char*)xB + ((size_t)(bm*256 + (t >> 3))) * (IN_F*2) + scol;
    const char* pB = (const char*)wB + ((size_t)(bn*256 + (t >> 3))) * (IN_F*2) + scol;
    const int tb16 = t * 16;

#define STAGE(pG, reg, h, tile) do {                                          \
    const char* _s = (pG) + (size_t)(tile)*128 + (size_t)(h)*(128*IN_F*2);    \
    char* _d = ldsc + (reg) + (h)*16384 + tb16;                               \
    gl_lds16(_s, _d);                                                         \
    gl_lds16(_s + (size_t)(64*IN_F*2), _d + 8192);                            \
} while (0)

    f32x4  acc[8][4] = {};
    bf16x8 b[4][2];
    bf16x8 a[2][2];

#define LOADB(reg) do {                                                       \
    _Pragma("unroll") for (int ni = 0; ni < 4; ++ni)                          \
    _Pragma("unroll") for (int kk = 0; kk < 2; ++kk)                          \
        b[ni][kk] = *(const bf16x8*)(ldsc + (reg) +                           \
                      ((bB + ni*2048 + kk*64) ^ sw));                         \
} while (0)

#define LOADA(reg, q) do {                                                    \
    _Pragma("unroll") for (int mm = 0; mm < 2; ++mm)                          \
    _Pragma("unroll") for (int kk = 0; kk < 2; ++kk)                          \
        a[mm][kk] = *(const bf16x8*)(ldsc + (reg) +                           \
                      ((bA + (2*(q)+mm)*4096 + kk*64) ^ sw));                 \
} while (0)

#define MFMAQ(q) do {                                                         \
    _Pragma("unroll") for (int mm = 0; mm < 2; ++mm)                          \
    _Pragma("unroll") for (int ni = 0; ni < 4; ++ni)                          \
    _Pragma("unroll") for (int kk = 0; kk < 2; ++kk)                          \
        acc[2*(q)+mm][ni] = __builtin_amdgcn_mfma_f32_16x16x32_bf16(          \
            a[mm][kk], b[ni][kk], acc[2*(q)+mm][ni], 0, 0, 0);                \
} while (0)

#define PH_TAIL(q)                                                            \
    __builtin_amdgcn_s_barrier();                                             \
    asm volatile("s_waitcnt lgkmcnt(0)" ::: "memory");                        \
    __builtin_amdgcn_s_setprio(1);                                            \
    MFMAQ(q);                                                                 \
    __builtin_amdgcn_s_setprio(0);                                            \
    __builtin_amdgcn_s_barrier();

    // ---- prologue: stage tile0 (4 half-tiles) + tile1 (B halves, A half0)
    STAGE(pB, LB0, 0, 0);
    STAGE(pB, LB0, 1, 0);
    STAGE(pA, LA0, 0, 0);
    STAGE(pA, LA0, 1, 0);
    STAGE(pB, LB1, 0, 1);
    STAGE(pB, LB1, 1, 1);
    STAGE(pA, LA1, 0, 1);
    asm volatile("s_waitcnt vmcnt(6)" ::: "memory");   // tile0's 4 half-tiles landed
    __builtin_amdgcn_s_barrier();

#pragma unroll 1
    for (int j = 0; j < IN_F/64/2; ++j) {
        const int to = 2*j + 1;
        const int se = (2*j + 2) & 63;   // wrapped tail staging targets free slots (safe)
        const int so = (2*j + 3) & 63;

        // ---- even tile (buf0) ----
        LOADB(LB0); LOADA(LA0, 0);
        STAGE(pA, LA1, 1, to);
        asm volatile("s_waitcnt lgkmcnt(8)" ::: "memory");
        PH_TAIL(0)
        LOADA(LA0, 1);
        STAGE(pB, LB0, 0, se);
        PH_TAIL(1)
        LOADA(LA0, 2);
        STAGE(pB, LB0, 1, se);
        PH_TAIL(2)
        LOADA(LA0, 3);
        STAGE(pA, LA0, 0, se);
        asm volatile("s_waitcnt vmcnt(6)" ::: "memory");
        PH_TAIL(3)

        // ---- odd tile (buf1) ----
        LOADB(LB1); LOADA(LA1, 0);
        STAGE(pA, LA0, 1, se);
        asm volatile("s_waitcnt lgkmcnt(8)" ::: "memory");
        PH_TAIL(0)
        LOADA(LA1, 1);
        STAGE(pB, LB1, 0, so);
        PH_TAIL(1)
        LOADA(LA1, 2);
        STAGE(pB, LB1, 1, so);
        PH_TAIL(2)
        LOADA(LA1, 3);
        STAGE(pA, LA1, 0, so);
        asm volatile("s_waitcnt vmcnt(6)" ::: "memory");
        PH_TAIL(3)
    }

    // ---- epilogue: C/D layout col=lane&15, row=(lane>>4)*4+q ; frag m at M-row 32m+16wm
    const int orow0 = bm*256 + 16*wm + ((lane >> 4) << 2);
    const int ocol0 = bn*256 + 64*wn + l15;
#pragma unroll
    for (int ni = 0; ni < 4; ++ni) {
        const int col = ocol0 + ni*16;
        const float bv = bias[col];
#pragma unroll
        for (int m = 0; m < 8; ++m) {
            const int r0 = orow0 + 32*m;
            f32x4 v = acc[m][ni];
#pragma unroll
            for (int q = 0; q < 4; ++q)
                out[(size_t)(r0 + q)*OUT_F + col] = v[q] + bv;
        }
    }
#undef STAGE
#undef LOADB
#undef LOADA
#undef MFMAQ
#undef PH_TAIL
}

extern "C" void kernel_launch(void* const* d_in, const int* in_sizes, int n_in,
                              void* d_out, int out_size, void* d_ws, size_t ws_size,
                              hipStream_t stream)
{
    const float* x    = (const float*)d_in[0];
    const float* W    = (const float*)d_in[1];
    const float* bias = (const float*)d_in[2];
    const float* U    = (const float*)d_in[3];
    const float* V    = (const float*)d_in[4];
    const float* A    = (const float*)d_in[5];
    const float* B    = (const float*)d_in[6];
    const float* R    = (const float*)d_in[7];
    const float* C    = (const float*)d_in[8];
    float* out = (float*)d_out;

    char* ws = (char*)d_ws;
    u16*      xB    = (u16*)(ws + XB_OFF);
    u16*      wB    = (u16*)(ws + WB_OFF);
    uint32_t* keys  = (uint32_t*)(ws + KEYS_OFF);
    uint32_t* ctl   = (uint32_t*)(ws + CTL_OFF);
    uint32_t* h1    = (uint32_t*)((char*)ctl + H1_OFF);
    uint32_t* h2    = (uint32_t*)((char*)ctl + H2_OFF);
    uint32_t* sel   = (uint32_t*)((char*)ctl + SEL_OFF);
    uint32_t* cnt3  = (uint32_t*)((char*)ctl + CNT3_OFF);
    uint32_t* list3 = (uint32_t*)((char*)ctl + LIST3_OFF);

    convx_kernel<<<TOKENS*IN_F/8/256, 256, 0, stream>>>(x, xB, ctl);
    prep_kernel<<<OUT_F/RPB, 256, 0, stream>>>(W, U, V, A, B, R, C, wB, keys, h1);
    select_kernel<<<1, 256, 0, stream>>>(h1, sel, 0);
    hist2_kernel<<<OUT_F, 256, 0, stream>>>(keys, sel, h2);
    select_kernel<<<1, 256, 0, stream>>>(h2, sel, 1);
    collect3_kernel<<<OUT_F, 256, 0, stream>>>(keys, sel, cnt3, list3);
    selfix_kernel<<<1, 256, 0, stream>>>(sel, cnt3, list3, wB);
    apply_kernel<<<OUT_F, 256, 0, stream>>>(keys, sel, wB);
    gemm256_kernel<<<(TOKENS/256)*(OUT_F/256), 512, 0, stream>>>(xB, wB, bias, out);
}

// Round 5
// 411.105 us; speedup vs baseline: 1.1166x; 1.1166x over previous
//
#include <hip/hip_runtime.h>
#include <stdint.h>

#define TOKENS 8192
#define OUT_F  4096
#define IN_F   4096
#define RNK    8
#define RPB    4
#define KPRUNE 8388608u
#define CAP3   16384u

typedef unsigned short u16;
typedef float  f32x4  __attribute__((ext_vector_type(4)));
typedef short  bf16x8 __attribute__((ext_vector_type(8)));
typedef unsigned short u16x8 __attribute__((ext_vector_type(8)));

// ---- workspace layout (bytes) ----
#define XB_OFF    0ull                 // xB  : 8192*4096 bf16 = 64 MiB
#define WB_OFF    67108864ull          // wB  : 4096*4096 bf16 = 32 MiB
#define KEYS_OFF  100663296ull         // keys: 4096*4096 u32  = 64 MiB
#define CTL_OFF   167772160ull
//   ctl: h1[4096] h2[4096] sel[8] cnt3[1] list3[CAP3]
#define H1_OFF    0
#define H2_OFF    16384
#define SEL_OFF   32768
#define CNT3_OFF  32800
#define LIST3_OFF 32804
#define CTL_ZERO_U32 8201              // h1+h2+sel+cnt3

__device__ __forceinline__ u16 f2bf(float f) {
    uint32_t u = __float_as_uint(f);
    u += 0x7fffu + ((u >> 16) & 1u);   // RNE
    return (u16)(u >> 16);
}

__device__ __forceinline__ uint32_t fkey(float s) {
    uint32_t u = __float_as_uint(s);
    return (u & 0x80000000u) ? ~u : (u | 0x80000000u);
}

// ---------------- x -> bf16 (+ ctl zeroing folded in) ----------------
__global__ void convx_kernel(const float* __restrict__ x, u16* __restrict__ xB,
                             uint32_t* __restrict__ ctl)
{
    const int t = threadIdx.x;
    if (blockIdx.x < 34) {
        const int i = blockIdx.x * 256 + t;
        if (i < CTL_ZERO_U32) ctl[i] = 0u;
    }
    const size_t idx = (size_t)blockIdx.x * 256 + t;
    const float4* xv = (const float4*)x;
    float4 a = xv[idx*2];
    float4 b = xv[idx*2 + 1];
    u16x8 o;
    o[0]=f2bf(a.x); o[1]=f2bf(a.y); o[2]=f2bf(a.z); o[3]=f2bf(a.w);
    o[4]=f2bf(b.x); o[5]=f2bf(b.y); o[6]=f2bf(b.z); o[7]=f2bf(b.w);
    *((u16x8*)xB + idx) = o;
}

// ---------------- prep: w, keys, bf16 w, 12-bit histogram (R3 known-good) ----------------
__global__ void prep_kernel(const float* __restrict__ W, const float* __restrict__ U,
                            const float* __restrict__ V, const float* __restrict__ A,
                            const float* __restrict__ B, const float* __restrict__ R,
                            const float* __restrict__ C, u16* __restrict__ wB,
                            uint32_t* __restrict__ keys, uint32_t* __restrict__ hist1)
{
    __shared__ uint32_t lh[4096];
    const int o0 = blockIdx.x * RPB, t = threadIdx.x;
    for (int b = t; b < 4096; b += 256) lh[b] = 0u;
    float uu[RPB][RNK], aa[RPB][RNK], ro[RPB];
#pragma unroll
    for (int r0 = 0; r0 < RPB; ++r0) {
#pragma unroll
        for (int r = 0; r < RNK; ++r) {
            uu[r0][r] = U[(o0+r0)*RNK + r];
            aa[r0][r] = A[(o0+r0)*RNK + r];
        }
        ro[r0] = R[o0 + r0];
    }
    __syncthreads();
    for (int j = 0; j < IN_F/256; ++j) {
        const int i = j*256 + t;
        float vv[RNK], bb[RNK];
#pragma unroll
        for (int r = 0; r < RNK; ++r) { vv[r] = V[r*IN_F + i]; bb[r] = B[r*IN_F + i]; }
        const float ci = C[i];
#pragma unroll
        for (int r0 = 0; r0 < RPB; ++r0) {
            float wv = W[(size_t)(o0+r0)*IN_F + i];
#pragma unroll
            for (int r = 0; r < RNK; ++r) wv = fmaf(uu[r0][r], vv[r], wv);
            float s = fabsf(wv);
#pragma unroll
            for (int r = 0; r < RNK; ++r) s = fmaf(aa[r0][r], bb[r], s);
            s += ro[r0] + ci;
            const uint32_t key = fkey(s);
            keys[(size_t)(o0+r0)*IN_F + i] = key;
            wB[(size_t)(o0+r0)*IN_F + i]   = f2bf(wv);
            atomicAdd(&lh[key >> 20], 1u);
        }
    }
    __syncthreads();
    for (int b = t; b < 4096; b += 256) { uint32_t c = lh[b]; if (c) atomicAdd(&hist1[b], c); }
}

// ---------------- k-th select over a 4096-bin histogram ----------------
// mode 0: hist1 (key>>20),      k=KPRUNE        -> sel[0]=b1, sel[1]=below
// mode 1: hist2 ((key>>8)&FFF), k=KPRUNE-sel[1] -> sel[2]=b2, sel[3]=total_below(24-bit prefix)
__global__ void select_kernel(const uint32_t* __restrict__ hist, uint32_t* sel, int mode)
{
    __shared__ uint32_t lh[4096];
    __shared__ uint32_t part[256];
    __shared__ uint32_t sseg[2];
    const int t = threadIdx.x;
    const uint32_t c1v = sel[1];
    const uint32_t k = (mode == 0) ? KPRUNE : (KPRUNE - c1v);
    for (int b = t; b < 4096; b += 256) lh[b] = hist[b];
    __syncthreads();
    uint32_t s = 0;
    for (int j = 0; j < 16; ++j) s += lh[t*16 + j];
    part[t] = s;
    __syncthreads();
    uint32_t pre = 0;
    for (int tt = 0; tt < t; ++tt) pre += part[tt];
    if (pre < k && pre + part[t] >= k) { sseg[0] = (uint32_t)t; sseg[1] = pre; }
    __syncthreads();
    const int seg = (int)sseg[0];
    const uint32_t accb = sseg[1];
    if (t < 16) {
        uint32_t pre2 = 0;
        for (int j = 0; j < t; ++j) pre2 += lh[seg*16 + j];
        const uint32_t c = lh[seg*16 + t];
        const uint32_t below = accb + pre2;
        if (below < k && below + c >= k) {
            const uint32_t bin = (uint32_t)(seg*16 + t);
            if (mode == 0) { sel[0] = bin; sel[1] = below; }
            else           { sel[2] = bin; sel[3] = c1v + below; }
        }
    }
}

// ---------------- hist level 2 ----------------
__global__ void hist2_kernel(const uint32_t* __restrict__ keys, const uint32_t* __restrict__ sel,
                             uint32_t* __restrict__ hist2)
{
    __shared__ uint32_t lh[4096];
    const int o = blockIdx.x, t = threadIdx.x;
    const uint32_t b1 = sel[0];
    for (int b = t; b < 4096; b += 256) lh[b] = 0u;
    __syncthreads();
    const uint32_t* kp = keys + (size_t)o*IN_F + t*16;
#pragma unroll
    for (int q = 0; q < 4; ++q) {
        uint4 kv = *(const uint4*)(kp + q*4);
        if ((kv.x >> 20) == b1) atomicAdd(&lh[(kv.x >> 8) & 0xFFFu], 1u);
        if ((kv.y >> 20) == b1) atomicAdd(&lh[(kv.y >> 8) & 0xFFFu], 1u);
        if ((kv.z >> 20) == b1) atomicAdd(&lh[(kv.z >> 8) & 0xFFFu], 1u);
        if ((kv.w >> 20) == b1) atomicAdd(&lh[(kv.w >> 8) & 0xFFFu], 1u);
    }
    __syncthreads();
    for (int b = t; b < 4096; b += 256) { uint32_t c = lh[b]; if (c) atomicAdd(&hist2[b], c); }
}

// ---------------- apply (merged): prune strict sub-prefix, collect prefix matches ----------------
// prune iff (key>>8) < pfx. Entries with (key>>8)==pfx are appended packed
// as (flat_idx<<8)|low8 and resolved exactly by selfix.
__global__ void apply_kernel(const uint32_t* __restrict__ keys, const uint32_t* __restrict__ sel,
                             u16* __restrict__ wB, uint32_t* __restrict__ cnt3,
                             uint32_t* __restrict__ list3)
{
    const uint32_t pfx = (sel[0] << 12) | sel[2];
    const size_t base = ((size_t)blockIdx.x * 256 + threadIdx.x) * 16;
    uint32_t kv[16];
#pragma unroll
    for (int q = 0; q < 4; ++q) *(uint4*)(kv + q*4) = *(const uint4*)(keys + base + q*4);
    uint4 wraw[2];
    wraw[0] = *(const uint4*)(wB + base);
    wraw[1] = *(const uint4*)(wB + base + 8);
    u16* wv = (u16*)wraw;
#pragma unroll
    for (int e = 0; e < 16; ++e) {
        const uint32_t hi = kv[e] >> 8;
        if (hi < pfx) wv[e] = 0u;
        else if (hi == pfx) {
            uint32_t s = atomicAdd(cnt3, 1u);
            if (s < CAP3) list3[s] = ((uint32_t)(base + e) << 8) | (kv[e] & 0xFFu);
        }
    }
    *(uint4*)(wB + base)     = wraw[0];
    *(uint4*)(wB + base + 8) = wraw[1];
}

// ---------------- selfix: final 8-bit select + exact stable pruning within prefix ----------------
__global__ void selfix_kernel(const uint32_t* __restrict__ sel, const uint32_t* __restrict__ cnt3,
                              const uint32_t* __restrict__ list3, u16* __restrict__ wB)
{
    __shared__ uint32_t lst[CAP3];
    __shared__ uint32_t hist[256];
    __shared__ uint32_t sv[2];
    const int t = threadIdx.x;
    uint32_t n = *cnt3; if (n > CAP3) n = CAP3;
    hist[t] = 0u;
    __syncthreads();
    for (uint32_t i = t; i < n; i += 256) {
        const uint32_t e = list3[i];
        lst[i] = e;
        atomicAdd(&hist[e & 0xFFu], 1u);
    }
    __syncthreads();
    const uint32_t k3 = KPRUNE - sel[3];     // >= 1, <= n
    uint32_t pre = 0;
    for (int b = 0; b < t; ++b) pre += hist[b];
    if (pre < k3 && pre + hist[t] >= k3) {
        sv[0] = (uint32_t)t;
        sv[1] = k3 - pre;                    // ties at b3 to prune (>=1)
    }
    __syncthreads();
    const uint32_t b3 = sv[0], p = sv[1];
    for (uint32_t i = t; i < n; i += 256) {
        const uint32_t e = lst[i];
        const uint32_t lo = e & 0xFFu;
        if (lo < b3) { wB[e >> 8] = 0u; continue; }
        if (lo != b3) continue;
        uint32_t rank = 0;
        for (uint32_t j = 0; j < n; ++j) {
            const uint32_t f = lst[j];
            rank += ((f & 0xFFu) == b3 && f < e) ? 1u : 0u;   // same low8 -> flat-idx order
        }
        if (rank < p) wB[e >> 8] = 0u;
    }
}

// ================= 256x256 8-phase bf16 NT GEMM (R3-verified schedule) =================
// BM=BN=256, BK=64, 8 waves (2M x 4N), LDS 128 KiB, T2 3-bit XOR swizzle
// (physical = logical ^ ((row&7)<<4), applied after the full logical offset).
// Linear block mapping (bn inner) — T1 XCD swizzle REGRESSED here (R4: FETCH +83%).
// Epilogue uses nontemporal stores so the 128 MB out-stream doesn't evict xB/wB from LLC.
#define LA0 0
#define LB0 32768
#define LA1 65536
#define LB1 98304

__device__ __forceinline__ void gl_lds16(const char* src, char* dst) {
    __builtin_amdgcn_global_load_lds((const __attribute__((address_space(1))) void*)src,
                                     (__attribute__((address_space(3))) void*)dst, 16, 0, 0);
}

__global__ __launch_bounds__(512, 2) void gemm256_kernel(const u16* __restrict__ xB,
                                                         const u16* __restrict__ wB,
                                                         const float* __restrict__ bias,
                                                         float* __restrict__ out)
{
    __shared__ char ldsc[131072];
    const int t    = threadIdx.x;
    const int lane = t & 63;
    const int wid  = t >> 6;
    const int wm   = wid >> 2;     // 0..1
    const int wn   = wid & 3;      // 0..3
    const int bid  = blockIdx.x;
    const int bn   = bid & 15;     // N/256 = 16
    const int bm   = bid >> 4;     // M/256 = 32

    const int l15 = lane & 15;
    const int kb  = (lane >> 4) << 4;               // 0,16,32,48 bytes (k-group)
    const int sw  = (lane & 7) << 4;                // 3-bit XOR swizzle
    const int bA  = (16*wm + l15) * 128 + kb;       // + m*4096 + kk*64, then ^ sw
    const int bB  = (64*wn + l15) * 128 + kb;       // + ni*2048 + kk*64, then ^ sw

    // staging: linear LDS dest [half*16384 + issue*8192 + t*16]; pre-swizzled global source
    const int scol = ((t & 7) * 16) ^ (((t >> 3) & 7) << 4);
    const char* pA = (const char*)xB + ((size_t)(bm*256 + (t >> 3))) * (IN_F*2) + scol;
    const char* pB = (const char*)wB + ((size_t)(bn*256 + (t >> 3))) * (IN_F*2) + scol;
    const int tb16 = t * 16;

#define STAGE(pG, reg, h, tile) do {                                          \
    const char* _s = (pG) + (size_t)(tile)*128 + (size_t)(h)*(128*IN_F*2);    \
    char* _d = ldsc + (reg) + (h)*16384 + tb16;                               \
    gl_lds16(_s, _d);                                                         \
    gl_lds16(_s + (size_t)(64*IN_F*2), _d + 8192);                            \
} while (0)

    f32x4  acc[8][4] = {};
    bf16x8 b[4][2];
    bf16x8 a[2][2];

#define LOADB(reg) do {                                                       \
    _Pragma("unroll") for (int ni = 0; ni < 4; ++ni)                          \
    _Pragma("unroll") for (int kk = 0; kk < 2; ++kk)                          \
        b[ni][kk] = *(const bf16x8*)(ldsc + (reg) +                           \
                      ((bB + ni*2048 + kk*64) ^ sw));                         \
} while (0)

#define LOADA(reg, q) do {                                                    \
    _Pragma("unroll") for (int mm = 0; mm < 2; ++mm)                          \
    _Pragma("unroll") for (int kk = 0; kk < 2; ++kk)                          \
        a[mm][kk] = *(const bf16x8*)(ldsc + (reg) +                           \
                      ((bA + (2*(q)+mm)*4096 + kk*64) ^ sw));                 \
} while (0)

#define MFMAQ(q) do {                                                         \
    _Pragma("unroll") for (int mm = 0; mm < 2; ++mm)                          \
    _Pragma("unroll") for (int ni = 0; ni < 4; ++ni)                          \
    _Pragma("unroll") for (int kk = 0; kk < 2; ++kk)                          \
        acc[2*(q)+mm][ni] = __builtin_amdgcn_mfma_f32_16x16x32_bf16(          \
            a[mm][kk], b[ni][kk], acc[2*(q)+mm][ni], 0, 0, 0);                \
} while (0)

#define PH_TAIL(q)                                                            \
    __builtin_amdgcn_s_barrier();                                             \
    asm volatile("s_waitcnt lgkmcnt(0)" ::: "memory");                        \
    __builtin_amdgcn_s_setprio(1);                                            \
    MFMAQ(q);                                                                 \
    __builtin_amdgcn_s_setprio(0);                                            \
    __builtin_amdgcn_s_barrier();

    // ---- prologue: stage tile0 (4 half-tiles) + tile1 (B halves, A half0)
    STAGE(pB, LB0, 0, 0);
    STAGE(pB, LB0, 1, 0);
    STAGE(pA, LA0, 0, 0);
    STAGE(pA, LA0, 1, 0);
    STAGE(pB, LB1, 0, 1);
    STAGE(pB, LB1, 1, 1);
    STAGE(pA, LA1, 0, 1);
    asm volatile("s_waitcnt vmcnt(6)" ::: "memory");   // tile0's 4 half-tiles landed
    __builtin_amdgcn_s_barrier();

#pragma unroll 1
    for (int j = 0; j < IN_F/64/2; ++j) {
        const int to = 2*j + 1;
        const int se = (2*j + 2) & 63;   // wrapped tail staging targets free slots (safe)
        const int so = (2*j + 3) & 63;

        // ---- even tile (buf0) ----
        LOADB(LB0); LOADA(LA0, 0);
        STAGE(pA, LA1, 1, to);
        asm volatile("s_waitcnt lgkmcnt(8)" ::: "memory");
        PH_TAIL(0)
        LOADA(LA0, 1);
        STAGE(pB, LB0, 0, se);
        PH_TAIL(1)
        LOADA(LA0, 2);
        STAGE(pB, LB0, 1, se);
        PH_TAIL(2)
        LOADA(LA0, 3);
        STAGE(pA, LA0, 0, se);
        asm volatile("s_waitcnt vmcnt(6)" ::: "memory");
        PH_TAIL(3)

        // ---- odd tile (buf1) ----
        LOADB(LB1); LOADA(LA1, 0);
        STAGE(pA, LA0, 1, se);
        asm volatile("s_waitcnt lgkmcnt(8)" ::: "memory");
        PH_TAIL(0)
        LOADA(LA1, 1);
        STAGE(pB, LB1, 0, so);
        PH_TAIL(1)
        LOADA(LA1, 2);
        STAGE(pB, LB1, 1, so);
        PH_TAIL(2)
        LOADA(LA1, 3);
        STAGE(pA, LA1, 0, so);
        asm volatile("s_waitcnt vmcnt(6)" ::: "memory");
        PH_TAIL(3)
    }

    // ---- epilogue: C/D layout col=lane&15, row=(lane>>4)*4+q ; frag m at M-row 32m+16wm
    const int orow0 = bm*256 + 16*wm + ((lane >> 4) << 2);
    const int ocol0 = bn*256 + 64*wn + l15;
#pragma unroll
    for (int ni = 0; ni < 4; ++ni) {
        const int col = ocol0 + ni*16;
        const float bv = bias[col];
#pragma unroll
        for (int m = 0; m < 8; ++m) {
            const int r0 = orow0 + 32*m;
            f32x4 v = acc[m][ni];
#pragma unroll
            for (int q = 0; q < 4; ++q)
                __builtin_nontemporal_store(v[q] + bv, &out[(size_t)(r0 + q)*OUT_F + col]);
        }
    }
#undef STAGE
#undef LOADB
#undef LOADA
#undef MFMAQ
#undef PH_TAIL
}

extern "C" void kernel_launch(void* const* d_in, const int* in_sizes, int n_in,
                              void* d_out, int out_size, void* d_ws, size_t ws_size,
                              hipStream_t stream)
{
    const float* x    = (const float*)d_in[0];
    const float* W    = (const float*)d_in[1];
    const float* bias = (const float*)d_in[2];
    const float* U    = (const float*)d_in[3];
    const float* V    = (const float*)d_in[4];
    const float* A    = (const float*)d_in[5];
    const float* B    = (const float*)d_in[6];
    const float* R    = (const float*)d_in[7];
    const float* C    = (const float*)d_in[8];
    float* out = (float*)d_out;

    char* ws = (char*)d_ws;
    u16*      xB    = (u16*)(ws + XB_OFF);
    u16*      wB    = (u16*)(ws + WB_OFF);
    uint32_t* keys  = (uint32_t*)(ws + KEYS_OFF);
    uint32_t* ctl   = (uint32_t*)(ws + CTL_OFF);
    uint32_t* h1    = (uint32_t*)((char*)ctl + H1_OFF);
    uint32_t* h2    = (uint32_t*)((char*)ctl + H2_OFF);
    uint32_t* sel   = (uint32_t*)((char*)ctl + SEL_OFF);
    uint32_t* cnt3  = (uint32_t*)((char*)ctl + CNT3_OFF);
    uint32_t* list3 = (uint32_t*)((char*)ctl + LIST3_OFF);

    convx_kernel<<<TOKENS*IN_F/8/256, 256, 0, stream>>>(x, xB, ctl);
    prep_kernel<<<OUT_F/RPB, 256, 0, stream>>>(W, U, V, A, B, R, C, wB, keys, h1);
    select_kernel<<<1, 256, 0, stream>>>(h1, sel, 0);
    hist2_kernel<<<OUT_F, 256, 0, stream>>>(keys, sel, h2);
    select_kernel<<<1, 256, 0, stream>>>(h2, sel, 1);
    apply_kernel<<<OUT_F, 256, 0, stream>>>(keys, sel, wB, cnt3, list3);
    selfix_kernel<<<1, 256, 0, stream>>>(sel, cnt3, list3, wB);
    gemm256_kernel<<<(TOKENS/256)*(OUT_F/256), 512, 0, stream>>>(xB, wB, bias, out);
}